// Round 3
// baseline (269.921 us; speedup 1.0000x reference)
//
#include <hip/hip_runtime.h>
#include <math.h>

#define NRAYS 8192
#define NS 128

typedef short bf16x8 __attribute__((ext_vector_type(8)));
typedef float f32x4  __attribute__((ext_vector_type(4)));

__device__ __host__ __forceinline__ unsigned short f2bf(float f) {
    union { float f; unsigned u; } v; v.f = f;
    unsigned r = v.u + 0x7FFFu + ((v.u >> 16) & 1u);
    return (unsigned short)(r >> 16);
}
__device__ __forceinline__ float bf2f(unsigned short u) {
    union { unsigned u; float f; } v; v.u = ((unsigned)u) << 16;
    return v.f;
}

// ---------------- prep kernel: pack w0/w1 into MFMA B-fragment order ----------------
__global__ void prep_weights(const float* __restrict__ w0,
                             const float* __restrict__ w1,
                             uint4* __restrict__ wsB)
{
    const int f = blockIdx.x;   // 0..47
    const int l = threadIdx.x;  // 0..63
    const float* W; int kvalid, ks, nt;
    if (f < 16) { ks = f >> 3; nt = f & 7; W = w0; kvalid = 39; }
    else        { int g = f - 16; ks = g >> 3; nt = g & 7; W = w1; kvalid = 128; }
    const int n  = nt * 16 + (l & 15);
    const int kb = ks * 32 + ((l >> 4) << 3);
    unsigned p[4];
    #pragma unroll
    for (int w = 0; w < 4; ++w) {
        int k0i = kb + 2 * w;
        float v0 = (k0i     < kvalid) ? W[(size_t)k0i * 128 + n]       : 0.0f;
        float v1 = (k0i + 1 < kvalid) ? W[(size_t)(k0i + 1) * 128 + n] : 0.0f;
        p[w] = (unsigned)f2bf(v0) | ((unsigned)f2bf(v1) << 16);
    }
    wsB[f * 64 + l] = make_uint4(p[0], p[1], p[2], p[3]);
}

// ---------------- kernel A: gather + featurize + alpha/scan ----------------
// One ray per block, 128 threads, tiny LDS -> high occupancy, max outstanding gathers.
__global__ __launch_bounds__(128, 4)
void featurize(const float* __restrict__ rays_o,
               const float* __restrict__ rays_d,
               const float* __restrict__ dgrid,   // (256,256,128,1)
               const float* __restrict__ k0g,     // (256,256,128,12)
               const float* __restrict__ ash,     // (128,)
               unsigned short* __restrict__ gfeat, // (1M,64) bf16
               float* __restrict__ gwgt,           // (1M,)
               float* __restrict__ galast)         // (8192,)
{
    const int r = blockIdx.x;
    const int p = threadIdx.x;     // 0..127
    const int lane = p & 63;

    const float ox = rays_o[3*r+0], oy = rays_o[3*r+1], oz = rays_o[3*r+2];
    const float dx = rays_d[3*r+0], dy = rays_d[3*r+1], dz = rays_d[3*r+2];

    const float tp = (float)p * (1.0f/127.0f);
    const float px = fmaf(dx, tp, ox);
    const float py = fmaf(dy, tp, oy);
    const float pz = fmaf(dz, tp, oz);

    float ux = (px + 1.0f) * (0.5f * 255.0f);
    float uy = (py + 1.0f) * (0.5f * 255.0f);
    float uz = pz * 127.0f;
    ux = fminf(fmaxf(ux, 0.0f), 255.0f);
    uy = fminf(fmaxf(uy, 0.0f), 255.0f);
    uz = fminf(fmaxf(uz, 0.0f), 127.0f);
    int ix = (int)ux; if (ix > 254) ix = 254;
    int iy = (int)uy; if (iy > 254) iy = 254;
    int iz = (int)uz; if (iz > 126) iz = 126;
    const float fx = ux - (float)ix;
    const float fy = uy - (float)iy;
    const float fz = uz - (float)iz;
    const float wx0 = 1.0f - fx, wy0 = 1.0f - fy, wz0 = 1.0f - fz;

    const int OX = 256*128, OY = 128;
    const int base = (ix * 256 + iy) * 128 + iz;
    float cw[8]; int cidx[8];
    cw[0]=wx0*wy0*wz0; cw[1]=wx0*wy0*fz; cw[2]=wx0*fy*wz0; cw[3]=wx0*fy*fz;
    cw[4]=fx*wy0*wz0;  cw[5]=fx*wy0*fz;  cw[6]=fx*fy*wz0;  cw[7]=fx*fy*fz;
    cidx[0]=base;        cidx[1]=base+1;
    cidx[2]=base+OY;     cidx[3]=base+OY+1;
    cidx[4]=base+OX;     cidx[5]=base+OX+1;
    cidx[6]=base+OX+OY;  cidx[7]=base+OX+OY+1;

    float dens = 0.0f;
    #pragma unroll
    for (int c = 0; c < 8; ++c) dens = fmaf(cw[c], dgrid[cidx[c]], dens);

    float feat[12];
    #pragma unroll
    for (int q = 0; q < 12; ++q) feat[q] = 0.0f;
    #pragma unroll
    for (int c = 0; c < 8; ++c) {
        const float4* p4 = reinterpret_cast<const float4*>(k0g + (size_t)cidx[c] * 12);
        const float4 a = p4[0], b = p4[1], d = p4[2];
        const float w = cw[c];
        feat[0]=fmaf(w,a.x,feat[0]); feat[1]=fmaf(w,a.y,feat[1]);
        feat[2]=fmaf(w,a.z,feat[2]); feat[3]=fmaf(w,a.w,feat[3]);
        feat[4]=fmaf(w,b.x,feat[4]); feat[5]=fmaf(w,b.y,feat[5]);
        feat[6]=fmaf(w,b.z,feat[6]); feat[7]=fmaf(w,b.w,feat[7]);
        feat[8]=fmaf(w,d.x,feat[8]); feat[9]=fmaf(w,d.y,feat[9]);
        feat[10]=fmaf(w,d.z,feat[10]); feat[11]=fmaf(w,d.w,feat[11]);
    }

    // xemb: cols 12..38 (27 values), col 39 = 0
    float e[28];
    e[0] = px; e[1] = py; e[2] = pz;
    {
        const float pc[3] = {px, py, pz};
        #pragma unroll
        for (int c = 0; c < 3; ++c) {
            #pragma unroll
            for (int f = 0; f < 4; ++f) {
                const float a = pc[c] * (float)(1 << f);
                e[3  + c*4 + f] = __sinf(a);
                e[15 + c*4 + f] = __cosf(a);
            }
        }
    }
    e[27] = 0.0f;

    // pack 64 bf16 cols: 0..11 k0, 12..38 xemb, 39..63 zero
    unsigned wds[32];
    #pragma unroll
    for (int q = 0; q < 6; ++q)
        wds[q] = (unsigned)f2bf(feat[2*q]) | ((unsigned)f2bf(feat[2*q+1]) << 16);
    #pragma unroll
    for (int q = 0; q < 14; ++q)
        wds[6+q] = (unsigned)f2bf(e[2*q]) | ((unsigned)f2bf(e[2*q+1]) << 16);
    #pragma unroll
    for (int q = 20; q < 32; ++q) wds[q] = 0u;

    uint4* dst = (uint4*)(gfeat + (size_t)(r * 128 + p) * 64);
    #pragma unroll
    for (int q = 0; q < 8; ++q)
        dst[q] = make_uint4(wds[4*q], wds[4*q+1], wds[4*q+2], wds[4*q+3]);

    // ---- alpha + shuffle-based cumprod scan ----
    const float shift = wz0 * ash[iz] + fz * ash[iz+1];
    const float dsh = dens + shift;
    const float sp  = fmaxf(dsh, 0.0f) + log1pf(expf(-fabsf(dsh)));
    const float alpha = 1.0f - expf(-2.0f * sp);    // INTERVAL = 2

    float v = 1.0f - alpha;     // inclusive product scan
    #pragma unroll
    for (int off = 1; off < 64; off <<= 1) {
        const float u = __shfl_up(v, off);
        if (lane >= off) v *= u;
    }
    __shared__ float s_w0tot;
    if (p == 63) s_w0tot = v;
    __syncthreads();
    if (p >= 64) v *= s_w0tot;
    float excl = __shfl_up(v, 1);
    if (p == 0)  excl = 1.0f;
    if (p == 64) excl = s_w0tot;

    gwgt[r * 128 + p] = alpha * excl;
    if (p == 127) galast[r] = v;
}

// ---------------- kernel B: MLP (MFMA) + composite ----------------
__global__ __launch_bounds__(256, 2)
void mlp_render(const unsigned short* __restrict__ gfeat,
                const float* __restrict__ gwgt,
                const float* __restrict__ galast,
                const float* __restrict__ rays_d,
                const float* __restrict__ w0,   // rows 39..65 used
                const float* __restrict__ b0,
                const float* __restrict__ b1,
                const float* __restrict__ w2,
                const float* __restrict__ b2,
                const uint4* __restrict__ wsB,
                float* __restrict__ out)
{
    __shared__ __align__(16) unsigned short sH[128][136];
    __shared__ float s_rayh[128];
    __shared__ float s_wgt[128];
    __shared__ float s_part[4][3];

    const int t = threadIdx.x;
    const int r = blockIdx.x;
    const int wv   = t >> 6;
    const int lane = t & 63;
    const int kgrp = lane >> 4;
    const int colb = lane & 15;

    // ---- pre-phase: rayh (threads 0..127), wgt load (threads 128..255) ----
    if (t < 128) {
        const int n = t;
        const float dx = rays_d[3*r+0], dy = rays_d[3*r+1], dz = rays_d[3*r+2];
        const float inv = rsqrtf(dx*dx + dy*dy + dz*dz);
        const float vx = dx*inv, vy = dy*inv, vz = dz*inv;
        float ve[27];
        ve[0] = vx; ve[1] = vy; ve[2] = vz;
        {
            const float vc[3] = {vx, vy, vz};
            #pragma unroll
            for (int c = 0; c < 3; ++c) {
                #pragma unroll
                for (int f = 0; f < 4; ++f) {
                    const float a = vc[c] * (float)(1 << f);
                    ve[3  + c*4 + f] = __sinf(a);
                    ve[15 + c*4 + f] = __cosf(a);
                }
            }
        }
        float acc = b0[n];
        #pragma unroll
        for (int i = 0; i < 27; ++i) acc = fmaf(ve[i], w0[(size_t)(39 + i) * 128 + n], acc);
        s_rayh[n] = acc;
    } else {
        s_wgt[t - 128] = gwgt[r * 128 + (t - 128)];
    }
    __syncthreads();

    // ---- L0: feat(128x64) @ w0T -> h0, A-frags streamed from global ----
    f32x4 C0[2][8];
    #pragma unroll
    for (int mt = 0; mt < 2; ++mt)
        #pragma unroll
        for (int nt = 0; nt < 8; ++nt) C0[mt][nt] = (f32x4){0.f,0.f,0.f,0.f};

    #pragma unroll
    for (int ks = 0; ks < 2; ++ks) {
        bf16x8 B[8];
        #pragma unroll
        for (int nt = 0; nt < 8; ++nt) {
            uint4 raw = wsB[(ks*8 + nt) * 64 + lane];
            B[nt] = *(bf16x8*)&raw;
        }
        bf16x8 A[2];
        #pragma unroll
        for (int mt = 0; mt < 2; ++mt) {
            const int row = wv*32 + mt*16 + colb;
            A[mt] = *(const bf16x8*)(gfeat + (size_t)(r*128 + row) * 64 + ks*32 + kgrp*8);
        }
        #pragma unroll
        for (int mt = 0; mt < 2; ++mt)
            #pragma unroll
            for (int nt = 0; nt < 8; ++nt)
                C0[mt][nt] = __builtin_amdgcn_mfma_f32_16x16x32_bf16(A[mt], B[nt], C0[mt][nt], 0, 0, 0);
    }

    {
        float rh[8];
        #pragma unroll
        for (int nt = 0; nt < 8; ++nt) rh[nt] = s_rayh[nt*16 + colb];
        #pragma unroll
        for (int mt = 0; mt < 2; ++mt)
            #pragma unroll
            for (int nt = 0; nt < 8; ++nt)
                #pragma unroll
                for (int rg = 0; rg < 4; ++rg) {
                    const int row = wv*32 + mt*16 + kgrp*4 + rg;
                    const float v = fmaxf(C0[mt][nt][rg] + rh[nt], 0.0f);
                    sH[row][nt*16 + colb] = f2bf(v);
                }
    }
    __syncthreads();

    // ---- L1: h0(128x128) @ w1T -> C1 (stays in registers) ----
    f32x4 C1[2][8];
    #pragma unroll
    for (int mt = 0; mt < 2; ++mt)
        #pragma unroll
        for (int nt = 0; nt < 8; ++nt) C1[mt][nt] = (f32x4){0.f,0.f,0.f,0.f};

    #pragma unroll
    for (int ks = 0; ks < 4; ++ks) {
        bf16x8 B[8];
        #pragma unroll
        for (int nt = 0; nt < 8; ++nt) {
            uint4 raw = wsB[(16 + ks*8 + nt) * 64 + lane];
            B[nt] = *(bf16x8*)&raw;
        }
        #pragma unroll
        for (int mt = 0; mt < 2; ++mt) {
            const int row = wv*32 + mt*16 + colb;
            bf16x8 A = *(const bf16x8*)&sH[row][ks*32 + kgrp*8];
            #pragma unroll
            for (int nt = 0; nt < 8; ++nt)
                C1[mt][nt] = __builtin_amdgcn_mfma_f32_16x16x32_bf16(A, B[nt], C1[mt][nt], 0, 0, 0);
        }
    }

    // ---- L2 (128->3) + sigmoid + composite, fully in registers ----
    {
        float bb[8], w2c[8][3];
        #pragma unroll
        for (int nt = 0; nt < 8; ++nt) {
            const int col = nt*16 + colb;
            bb[nt] = b1[col];
            w2c[nt][0] = w2[col*3+0];
            w2c[nt][1] = w2[col*3+1];
            w2c[nt][2] = w2[col*3+2];
        }
        const float bias0 = b2[0], bias1 = b2[1], bias2 = b2[2];
        float c0 = 0.f, c1 = 0.f, c2 = 0.f;
        #pragma unroll
        for (int mt = 0; mt < 2; ++mt)
            #pragma unroll
            for (int rg = 0; rg < 4; ++rg) {
                const int row = wv*32 + mt*16 + kgrp*4 + rg;
                float o0 = 0.f, o1 = 0.f, o2 = 0.f;
                #pragma unroll
                for (int nt = 0; nt < 8; ++nt) {
                    const float h = fmaxf(C1[mt][nt][rg] + bb[nt], 0.0f);
                    o0 = fmaf(h, w2c[nt][0], o0);
                    o1 = fmaf(h, w2c[nt][1], o1);
                    o2 = fmaf(h, w2c[nt][2], o2);
                }
                #pragma unroll
                for (int off = 1; off <= 8; off <<= 1) {
                    o0 += __shfl_xor(o0, off);
                    o1 += __shfl_xor(o1, off);
                    o2 += __shfl_xor(o2, off);
                }
                if (colb == 0) {
                    const float wg = s_wgt[row];
                    c0 += wg / (1.0f + expf(-(o0 + bias0)));
                    c1 += wg / (1.0f + expf(-(o1 + bias1)));
                    c2 += wg / (1.0f + expf(-(o2 + bias2)));
                }
            }
        c0 += __shfl_down(c0, 32); c0 += __shfl_down(c0, 16);
        c1 += __shfl_down(c1, 32); c1 += __shfl_down(c1, 16);
        c2 += __shfl_down(c2, 32); c2 += __shfl_down(c2, 16);
        if (lane == 0) { s_part[wv][0] = c0; s_part[wv][1] = c1; s_part[wv][2] = c2; }
    }
    __syncthreads();
    if (t == 0) {
        const float alast = galast[r];
        out[3*r+0] = s_part[0][0] + s_part[1][0] + s_part[2][0] + s_part[3][0] + alast;
        out[3*r+1] = s_part[0][1] + s_part[1][1] + s_part[2][1] + s_part[3][1] + alast;
        out[3*r+2] = s_part[0][2] + s_part[1][2] + s_part[2][2] + s_part[3][2] + alast;
    }
}

// ---------------- fallback fused kernel (round-2, used if ws too small) ----------------
__global__ __launch_bounds__(256, 2)
void mpi_fused(const float* __restrict__ rays_o,
               const float* __restrict__ rays_d,
               const float* __restrict__ dgrid,
               const float* __restrict__ k0g,
               const float* __restrict__ ash,
               const float* __restrict__ w0,
               const float* __restrict__ b0,
               const float* __restrict__ b1,
               const float* __restrict__ w2,
               const float* __restrict__ b2,
               const uint4* __restrict__ wsB,
               float* __restrict__ out)
{
    __shared__ __align__(16) unsigned short sA[128][72];
    __shared__ __align__(16) unsigned short sH[128][136];
    __shared__ float s_scan[128];
    __shared__ float s_wgt[128];
    __shared__ float s_rayh[128];
    __shared__ float s_part[4][3];

    const int t = threadIdx.x;
    const int r = blockIdx.x;

    const float ox = rays_o[3*r+0], oy = rays_o[3*r+1], oz = rays_o[3*r+2];
    const float dx = rays_d[3*r+0], dy = rays_d[3*r+1], dz = rays_d[3*r+2];

    float alpha = 0.0f;

    if (t < 128) {
        const int p = t;
        const float tp = (float)p * (1.0f/127.0f);
        const float px = fmaf(dx, tp, ox);
        const float py = fmaf(dy, tp, oy);
        const float pz = fmaf(dz, tp, oz);

        float ux = (px + 1.0f) * (0.5f * 255.0f);
        float uy = (py + 1.0f) * (0.5f * 255.0f);
        float uz = pz * 127.0f;
        ux = fminf(fmaxf(ux, 0.0f), 255.0f);
        uy = fminf(fmaxf(uy, 0.0f), 255.0f);
        uz = fminf(fmaxf(uz, 0.0f), 127.0f);
        int ix = (int)ux; if (ix > 254) ix = 254;
        int iy = (int)uy; if (iy > 254) iy = 254;
        int iz = (int)uz; if (iz > 126) iz = 126;
        const float fx = ux - (float)ix;
        const float fy = uy - (float)iy;
        const float fz = uz - (float)iz;
        const float wx0 = 1.0f - fx, wy0 = 1.0f - fy, wz0 = 1.0f - fz;

        const int OX = 256*128, OY = 128;
        const int base = (ix * 256 + iy) * 128 + iz;
        float cw[8]; int cidx[8];
        cw[0]=wx0*wy0*wz0; cw[1]=wx0*wy0*fz; cw[2]=wx0*fy*wz0; cw[3]=wx0*fy*fz;
        cw[4]=fx*wy0*wz0;  cw[5]=fx*wy0*fz;  cw[6]=fx*fy*wz0;  cw[7]=fx*fy*fz;
        cidx[0]=base;        cidx[1]=base+1;
        cidx[2]=base+OY;     cidx[3]=base+OY+1;
        cidx[4]=base+OX;     cidx[5]=base+OX+1;
        cidx[6]=base+OX+OY;  cidx[7]=base+OX+OY+1;

        float dens = 0.0f;
        #pragma unroll
        for (int c = 0; c < 8; ++c) dens = fmaf(cw[c], dgrid[cidx[c]], dens);

        float feat[12];
        #pragma unroll
        for (int q = 0; q < 12; ++q) feat[q] = 0.0f;
        #pragma unroll
        for (int c = 0; c < 8; ++c) {
            const float4* p4 = reinterpret_cast<const float4*>(k0g + (size_t)cidx[c] * 12);
            const float4 a = p4[0], b = p4[1], d = p4[2];
            const float w = cw[c];
            feat[0]=fmaf(w,a.x,feat[0]); feat[1]=fmaf(w,a.y,feat[1]);
            feat[2]=fmaf(w,a.z,feat[2]); feat[3]=fmaf(w,a.w,feat[3]);
            feat[4]=fmaf(w,b.x,feat[4]); feat[5]=fmaf(w,b.y,feat[5]);
            feat[6]=fmaf(w,b.z,feat[6]); feat[7]=fmaf(w,b.w,feat[7]);
            feat[8]=fmaf(w,d.x,feat[8]); feat[9]=fmaf(w,d.y,feat[9]);
            feat[10]=fmaf(w,d.z,feat[10]); feat[11]=fmaf(w,d.w,feat[11]);
        }
        #pragma unroll
        for (int q = 0; q < 6; ++q) {
            unsigned pk = (unsigned)f2bf(feat[2*q]) | ((unsigned)f2bf(feat[2*q+1]) << 16);
            *(unsigned*)&sA[p][2*q] = pk;
        }

        const float shift = wz0 * ash[iz] + fz * ash[iz+1];
        const float dsh = dens + shift;
        const float sp  = fmaxf(dsh, 0.0f) + log1pf(expf(-fabsf(dsh)));
        alpha = 1.0f - expf(-2.0f * sp);
        s_scan[p] = 1.0f - alpha;
    } else {
        const int q = t - 128;
        const float tp = (float)q * (1.0f/127.0f);
        const float px = fmaf(dx, tp, ox);
        const float py = fmaf(dy, tp, oy);
        const float pz = fmaf(dz, tp, oz);

        sA[q][12] = f2bf(px); sA[q][13] = f2bf(py); sA[q][14] = f2bf(pz);
        {
            const float pc[3] = {px, py, pz};
            #pragma unroll
            for (int c = 0; c < 3; ++c) {
                #pragma unroll
                for (int f = 0; f < 4; ++f) {
                    const float a = pc[c] * (float)(1 << f);
                    sA[q][15 + c*4 + f] = f2bf(__sinf(a));
                    sA[q][27 + c*4 + f] = f2bf(__cosf(a));
                }
            }
        }
        sA[q][39] = 0;
        #pragma unroll
        for (int c = 0; c < 12; ++c) *(unsigned*)&sA[q][40 + 2*c] = 0u;

        const float inv = rsqrtf(dx*dx + dy*dy + dz*dz);
        const float vx = dx*inv, vy = dy*inv, vz = dz*inv;
        float ve[27];
        ve[0] = vx; ve[1] = vy; ve[2] = vz;
        {
            const float vc[3] = {vx, vy, vz};
            #pragma unroll
            for (int c = 0; c < 3; ++c) {
                #pragma unroll
                for (int f = 0; f < 4; ++f) {
                    const float a = vc[c] * (float)(1 << f);
                    ve[3  + c*4 + f] = __sinf(a);
                    ve[15 + c*4 + f] = __cosf(a);
                }
            }
        }
        const int n = q;
        float acc = b0[n];
        #pragma unroll
        for (int i = 0; i < 27; ++i) acc = fmaf(ve[i], w0[(size_t)(39 + i) * 128 + n], acc);
        s_rayh[n] = acc;
    }
    __syncthreads();

    #pragma unroll
    for (int off = 1; off < 128; off <<= 1) {
        float v = 0.0f, pr = 1.0f;
        if (t < 128) { v = s_scan[t]; pr = (t >= off) ? s_scan[t - off] : 1.0f; }
        __syncthreads();
        if (t < 128) s_scan[t] = v * pr;
        __syncthreads();
    }
    if (t < 128) s_wgt[t] = alpha * ((t == 0) ? 1.0f : s_scan[t - 1]);
    __syncthreads();

    const int wv   = t >> 6;
    const int lane = t & 63;
    const int kgrp = lane >> 4;
    const int colb = lane & 15;

    f32x4 C0[2][8];
    #pragma unroll
    for (int mt = 0; mt < 2; ++mt)
        #pragma unroll
        for (int nt = 0; nt < 8; ++nt) C0[mt][nt] = (f32x4){0.f,0.f,0.f,0.f};

    #pragma unroll
    for (int ks = 0; ks < 2; ++ks) {
        bf16x8 B[8];
        #pragma unroll
        for (int nt = 0; nt < 8; ++nt) {
            uint4 raw = wsB[(ks*8 + nt) * 64 + lane];
            B[nt] = *(bf16x8*)&raw;
        }
        #pragma unroll
        for (int mt = 0; mt < 2; ++mt) {
            const int row = wv*32 + mt*16 + colb;
            bf16x8 A = *(const bf16x8*)&sA[row][ks*32 + kgrp*8];
            #pragma unroll
            for (int nt = 0; nt < 8; ++nt)
                C0[mt][nt] = __builtin_amdgcn_mfma_f32_16x16x32_bf16(A, B[nt], C0[mt][nt], 0, 0, 0);
        }
    }

    {
        float rh[8];
        #pragma unroll
        for (int nt = 0; nt < 8; ++nt) rh[nt] = s_rayh[nt*16 + colb];
        #pragma unroll
        for (int mt = 0; mt < 2; ++mt)
            #pragma unroll
            for (int nt = 0; nt < 8; ++nt)
                #pragma unroll
                for (int rg = 0; rg < 4; ++rg) {
                    const int row = wv*32 + mt*16 + kgrp*4 + rg;
                    const float v = fmaxf(C0[mt][nt][rg] + rh[nt], 0.0f);
                    sH[row][nt*16 + colb] = f2bf(v);
                }
    }
    __syncthreads();

    f32x4 C1[2][8];
    #pragma unroll
    for (int mt = 0; mt < 2; ++mt)
        #pragma unroll
        for (int nt = 0; nt < 8; ++nt) C1[mt][nt] = (f32x4){0.f,0.f,0.f,0.f};

    #pragma unroll
    for (int ks = 0; ks < 4; ++ks) {
        bf16x8 B[8];
        #pragma unroll
        for (int nt = 0; nt < 8; ++nt) {
            uint4 raw = wsB[(16 + ks*8 + nt) * 64 + lane];
            B[nt] = *(bf16x8*)&raw;
        }
        #pragma unroll
        for (int mt = 0; mt < 2; ++mt) {
            const int row = wv*32 + mt*16 + colb;
            bf16x8 A = *(const bf16x8*)&sH[row][ks*32 + kgrp*8];
            #pragma unroll
            for (int nt = 0; nt < 8; ++nt)
                C1[mt][nt] = __builtin_amdgcn_mfma_f32_16x16x32_bf16(A, B[nt], C1[mt][nt], 0, 0, 0);
        }
    }

    {
        float bb[8], w2c[8][3];
        #pragma unroll
        for (int nt = 0; nt < 8; ++nt) {
            const int col = nt*16 + colb;
            bb[nt] = b1[col];
            w2c[nt][0] = w2[col*3+0];
            w2c[nt][1] = w2[col*3+1];
            w2c[nt][2] = w2[col*3+2];
        }
        const float bias0 = b2[0], bias1 = b2[1], bias2 = b2[2];
        float c0 = 0.f, c1 = 0.f, c2 = 0.f;
        #pragma unroll
        for (int mt = 0; mt < 2; ++mt)
            #pragma unroll
            for (int rg = 0; rg < 4; ++rg) {
                const int row = wv*32 + mt*16 + kgrp*4 + rg;
                float o0 = 0.f, o1 = 0.f, o2 = 0.f;
                #pragma unroll
                for (int nt = 0; nt < 8; ++nt) {
                    const float h = fmaxf(C1[mt][nt][rg] + bb[nt], 0.0f);
                    o0 = fmaf(h, w2c[nt][0], o0);
                    o1 = fmaf(h, w2c[nt][1], o1);
                    o2 = fmaf(h, w2c[nt][2], o2);
                }
                #pragma unroll
                for (int off = 1; off <= 8; off <<= 1) {
                    o0 += __shfl_xor(o0, off);
                    o1 += __shfl_xor(o1, off);
                    o2 += __shfl_xor(o2, off);
                }
                if (colb == 0) {
                    const float wg = s_wgt[row];
                    c0 += wg / (1.0f + expf(-(o0 + bias0)));
                    c1 += wg / (1.0f + expf(-(o1 + bias1)));
                    c2 += wg / (1.0f + expf(-(o2 + bias2)));
                }
            }
        c0 += __shfl_down(c0, 32); c0 += __shfl_down(c0, 16);
        c1 += __shfl_down(c1, 32); c1 += __shfl_down(c1, 16);
        c2 += __shfl_down(c2, 32); c2 += __shfl_down(c2, 16);
        if (lane == 0) { s_part[wv][0] = c0; s_part[wv][1] = c1; s_part[wv][2] = c2; }
    }
    __syncthreads();
    if (t == 0) {
        const float alast = s_scan[127];
        out[3*r+0] = s_part[0][0] + s_part[1][0] + s_part[2][0] + s_part[3][0] + alast;
        out[3*r+1] = s_part[0][1] + s_part[1][1] + s_part[2][1] + s_part[3][1] + alast;
        out[3*r+2] = s_part[0][2] + s_part[1][2] + s_part[2][2] + s_part[3][2] + alast;
    }
}

extern "C" void kernel_launch(void* const* d_in, const int* in_sizes, int n_in,
                              void* d_out, int out_size, void* d_ws, size_t ws_size,
                              hipStream_t stream) {
    const float* rays_o = (const float*)d_in[0];
    const float* rays_d = (const float*)d_in[1];
    const float* dgrid  = (const float*)d_in[2];
    const float* k0g    = (const float*)d_in[3];
    const float* ash    = (const float*)d_in[4];
    const float* w0     = (const float*)d_in[5];
    const float* b0     = (const float*)d_in[6];
    const float* w1     = (const float*)d_in[7];
    const float* b1     = (const float*)d_in[8];
    const float* w2     = (const float*)d_in[9];
    const float* b2     = (const float*)d_in[10];
    float* out = (float*)d_out;

    // ws layout
    const size_t WSB_BYTES   = 48u * 64u * 16u;                 // 49152
    const size_t FEAT_BYTES  = (size_t)NRAYS * NS * 64 * 2;     // 134217728
    const size_t WGT_BYTES   = (size_t)NRAYS * NS * 4;          // 4194304
    const size_t ALAST_BYTES = (size_t)NRAYS * 4;               // 32768
    const size_t NEEDED = WSB_BYTES + FEAT_BYTES + WGT_BYTES + ALAST_BYTES;

    uint4* wsB = (uint4*)d_ws;
    prep_weights<<<48, 64, 0, stream>>>(w0, w1, wsB);

    if (ws_size >= NEEDED) {
        unsigned short* gfeat = (unsigned short*)((char*)d_ws + WSB_BYTES);
        float* gwgt   = (float*)((char*)d_ws + WSB_BYTES + FEAT_BYTES);
        float* galast = (float*)((char*)d_ws + WSB_BYTES + FEAT_BYTES + WGT_BYTES);

        featurize<<<NRAYS, NS, 0, stream>>>(rays_o, rays_d, dgrid, k0g, ash,
                                            gfeat, gwgt, galast);
        mlp_render<<<NRAYS, 256, 0, stream>>>(gfeat, gwgt, galast, rays_d,
                                              w0, b0, b1, w2, b2, wsB, out);
    } else {
        mpi_fused<<<NRAYS, 256, 0, stream>>>(rays_o, rays_d, dgrid, k0g, ash,
                                             w0, b0, b1, w2, b2, wsB, out);
    }
}